// Round 13
// baseline (210.758 us; speedup 1.0000x reference)
//
#include <hip/hip_runtime.h>
#include <hip/hip_bf16.h>
#include <stdint.h>

// Problem constants (B,C,H,W = 32,256,64,64; E=4, O=256, K=3)
#define NB 32
#define NC 256
#define NH 64
#define NW 64
#define NE 4
#define NO 256

typedef __bf16 bf16x8 __attribute__((ext_vector_type(8)));
typedef float  f32x4  __attribute__((ext_vector_type(4)));

__device__ __forceinline__ unsigned short f2bf(float f) {
  union { float f; uint32_t u; } v; v.f = f;
  uint32_t u = v.u;
  uint32_t r = (u + 0x7FFFu + ((u >> 16) & 1u)) >> 16;  // RNE
  return (unsigned short)r;
}

// =====================================================================
// NEW PATH
// =====================================================================

// ---- Kernel A: transpose x (NCHW fp32) -> xT (NHWC bf16) + per-(b,h) rowsums
__global__ __launch_bounds__(256) void xt_k(const float* __restrict__ x,
                                            unsigned short* __restrict__ xT,
                                            float* __restrict__ rowsum) {
  const int bh = blockIdx.x;            // b*64 + h
  const int tid = threadIdx.x;
  const int ci = tid >> 4;              // 0..15 channel-in-pass
  const int wq = (tid & 15) * 4;        // w quad
  __shared__ unsigned short t_lds[256 * 66];

#pragma unroll 4
  for (int p = 0; p < 16; ++p) {
    const int c = p * 16 + ci;
    const float4 v = *(const float4*)&x[(((size_t)(blockIdx.x >> 6) * 256 + c) * 64 +
                                         (bh & 63)) * 64 + wq];
    uint32_t p0 = (uint32_t)f2bf(v.x) | ((uint32_t)f2bf(v.y) << 16);
    uint32_t p1 = (uint32_t)f2bf(v.z) | ((uint32_t)f2bf(v.w) << 16);
    *(uint32_t*)&t_lds[c * 66 + wq]     = p0;
    *(uint32_t*)&t_lds[c * 66 + wq + 2] = p1;
    float s = (v.x + v.y) + (v.z + v.w);
    s += __shfl_down(s, 8, 16);
    s += __shfl_down(s, 4, 16);
    s += __shfl_down(s, 2, 16);
    s += __shfl_down(s, 1, 16);
    if ((tid & 15) == 0) rowsum[((size_t)bh << 8) + c] = s;
  }
  __syncthreads();
#pragma unroll
  for (int i = 0; i < 8; ++i) {
    const int m  = tid + (i << 8);
    const int w  = m >> 5;
    const int cg = m & 31;
    uint32_t q0 = (uint32_t)t_lds[(cg * 8 + 0) * 66 + w] |
                  ((uint32_t)t_lds[(cg * 8 + 1) * 66 + w] << 16);
    uint32_t q1 = (uint32_t)t_lds[(cg * 8 + 2) * 66 + w] |
                  ((uint32_t)t_lds[(cg * 8 + 3) * 66 + w] << 16);
    uint32_t q2 = (uint32_t)t_lds[(cg * 8 + 4) * 66 + w] |
                  ((uint32_t)t_lds[(cg * 8 + 5) * 66 + w] << 16);
    uint32_t q3 = (uint32_t)t_lds[(cg * 8 + 6) * 66 + w] |
                  ((uint32_t)t_lds[(cg * 8 + 7) * 66 + w] << 16);
    uint4 q = {q0, q1, q2, q3};
    *(uint4*)&xT[(((size_t)bh << 6) + w) * 256 + cg * 8] = q;
  }
}

// ---- Kernel B: reduce rowsums -> pooled -> logits -> softmax -> attn; zero zpage
__global__ __launch_bounds__(256) void router2_k(const float* __restrict__ rowsum,
                                                 const float* __restrict__ rw,
                                                 const float* __restrict__ rb,
                                                 float* __restrict__ attn,
                                                 uint32_t* __restrict__ zpage) {
  const int b = blockIdx.x, tid = threadIdx.x;
  if (b == 0) { uint4 z = {0, 0, 0, 0}; ((uint4*)zpage)[tid] = z; }
  float s = 0.f;
#pragma unroll 8
  for (int h = 0; h < 64; ++h) s += rowsum[((size_t)(b * 64 + h) << 8) + tid];
  __shared__ float pl[256];
  __shared__ float lg[4];
  pl[tid] = s * (1.f / 4096.f);
  __syncthreads();
  const int e = tid >> 6, ln = tid & 63;
  float d = pl[ln]       * rw[e * 256 + ln] +
            pl[ln + 64]  * rw[e * 256 + ln + 64] +
            pl[ln + 128] * rw[e * 256 + ln + 128] +
            pl[ln + 192] * rw[e * 256 + ln + 192];
#pragma unroll
  for (int off = 32; off > 0; off >>= 1) d += __shfl_down(d, off, 64);
  if (ln == 0) lg[e] = d + rb[e];
  __syncthreads();
  if (tid == 0) {
    float l0 = lg[0], l1 = lg[1], l2 = lg[2], l3 = lg[3];
    float m  = fmaxf(fmaxf(l0, l1), fmaxf(l2, l3));
    float e0 = expf(l0 - m), e1 = expf(l1 - m), e2 = expf(l2 - m), e3 = expf(l3 - m);
    float inv = 1.f / (e0 + e1 + e2 + e3);
    attn[b * 4 + 0] = e0 * inv;
    attn[b * 4 + 1] = e1 * inv;
    attn[b * 4 + 2] = e2 * inv;
    attn[b * 4 + 3] = e3 * inv;
  }
}

// ---- Kernel C: mixed weights; each thread owns one (t,cb,o,c32), loops over b
__global__ __launch_bounds__(256) void wmix_k2(const float* __restrict__ ew,
                                               const float* __restrict__ attn,
                                               unsigned short* __restrict__ wmix) {
  __shared__ float at[128];
  if (threadIdx.x < 128) at[threadIdx.x] = attn[threadIdx.x];
  __syncthreads();
  const int i   = blockIdx.x * 256 + threadIdx.x;   // 0..589823
  const int c32 = i & 31;
  const int o   = (i >> 5) & 255;
  const int cb  = (i >> 13) & 7;
  const int t   = i >> 16;                          // 0..8
  const int c   = cb * 32 + c32;
  const size_t estride = (size_t)NO * NC * 9;       // 589824
  const size_t wi = ((size_t)o * NC + c) * 9 + t;
  const float e0 = ew[wi], e1 = ew[wi + estride], e2 = ew[wi + 2 * estride],
              e3 = ew[wi + 3 * estride];
  const size_t outbase = ((size_t)t * 8 + cb) * 8192 + o * 32 + c32;
#pragma unroll 4
  for (int b = 0; b < 32; ++b) {
    float s = at[b * 4] * e0 + at[b * 4 + 1] * e1 + at[b * 4 + 2] * e2 +
              at[b * 4 + 3] * e3;
    wmix[outbase + (size_t)b * 589824] = f2bf(s);
  }
}

// ---- Kernel D (R13 = R12 fixed): R11 shape, kw-major tap order with X
// row-frag reuse. Per kw-group: 16 ds_read_b128 instead of 24 (-33% LDS
// traffic); 2 of 3 taps start their first MFMA cluster on already-resident
// registers, de-correlating phase-locked LDS bursts. W consumed order
// [0,3,6,1,4,7,2,5,8]; same A/B rotation parity (9 odd -> swap per chunk).
__global__ __launch_bounds__(256, 2) void conv_k8(
    const unsigned short* __restrict__ xT, const unsigned short* __restrict__ wmix,
    float* __restrict__ y) {
  const int bid   = blockIdx.x;        // 1024 blocks
  const int r     = bid >> 3;          // 0..127
  const int ptile = r & 15;            // 16 tiles of 4 rows
  const int ob    = ((r >> 4) & 1) * 128;
  const int b     = (bid & 7) + ((r >> 5) << 3);
  const int tid   = threadIdx.x;
  const int lane  = tid & 63;
  const int wid   = tid >> 6;          // 0..3
  const int wm    = (wid >> 1) * 64;   // O half
  const int rp    = wid & 1;           // row-pair within 4-row tile
  const int h0    = ptile * 4;
  const int lm    = lane & 15;
  const int lq    = lane >> 4;

  // 6 halo rows x 66 cols x 32 ch bf16 = 25344 B; padded to 25600 B
  __shared__ unsigned short xlds[2][12800];

  // Persistent staging offsets (elements, relative to xT). Zero-page lanes
  // point at xT + 64MB (zpage) and step +32/chunk (drift <=448B, zeroed).
  uint32_t soff[7];
#pragma unroll
  for (int i = 0; i < 7; ++i) {
    const int chunk = wid + 4 * i;
    const int d   = chunk * 64 + lane;
    const int row = d / 264;
    const int rem = d - row * 264;
    const int col = rem >> 2;
    const int s   = rem & 3;
    const int g   = s ^ ((col >> 1) & 3);
    const int gh  = h0 - 1 + row;
    const int w   = col - 1;
    const bool ok = (d < 1584) && (gh >= 0) && (gh < NH) && (w >= 0) && (w < NW);
    soff[i] = ok ? (uint32_t)(((b * 64 + gh) * 64 + w) << 8) + g * 8
                 : 33554432u + lane * 8;   // -> zpage
  }

  auto stage = [&](int buf) {
#pragma unroll
    for (int i = 0; i < 7; ++i) {
      const int chunk = wid + 4 * i;
      if (chunk < 25) {   // wave-uniform
        const unsigned short* src = xT + soff[i];
        char* dst = (char*)&xlds[buf][0] + chunk * 1024;
        __builtin_amdgcn_global_load_lds(
            (const __attribute__((address_space(1))) void*)src,
            (__attribute__((address_space(3))) void*)dst, 16, 0, 0);
      }
      soff[i] += 32;   // next c-chunk (64B)
    }
  };

  // Swizzled byte offset per kw (col-group -> +1024B imm; row -> +4224B imm).
  uint32_t xpo[3];
#pragma unroll
  for (int kw = 0; kw < 3; ++kw) {
    const int col = lm + kw;
    xpo[kw] = (uint32_t)(rp * 8448) +
              (((uint32_t)col << 6) | ((uint32_t)(lq ^ ((col >> 1) & 3)) << 4));
  }

  f32x4 acc[4][8];
#pragma unroll
  for (int i = 0; i < 4; ++i)
#pragma unroll
    for (int j = 0; j < 8; ++j) acc[i][j] = {0.f, 0.f, 0.f, 0.f};

  // Loop-carried W pointer; set (t,cb) base = (t*8+cb)*8192 elements.
  const unsigned short* wptr =
      wmix + (size_t)b * 589824 + (ob + wm + lm) * 32 + lq * 8;

  bf16x8 wa0, wa1, wa2, wa3, wb0, wb1, wb2, wb3;
  bf16x8 xa0, xa1, xa2, xa3, xb0, xb1, xb2, xb3;

#define WLOAD(L0, L1, L2, L3, delta)                                          \
  {                                                                           \
    L0 = *(const bf16x8*)(wptr);                                              \
    L1 = *(const bf16x8*)(wptr + 512);                                        \
    L2 = *(const bf16x8*)(wptr + 1024);                                       \
    L3 = *(const bf16x8*)(wptr + 1536);                                       \
    wptr += (delta);                                                          \
  }

#define XLOAD(q0, q1, q2, q3, XB_, boff)                                      \
  {                                                                           \
    q0 = *(const bf16x8*)((XB_) + (boff));                                    \
    q1 = *(const bf16x8*)((XB_) + (boff) + 1024);                             \
    q2 = *(const bf16x8*)((XB_) + (boff) + 2048);                             \
    q3 = *(const bf16x8*)((XB_) + (boff) + 3072);                             \
  }

// 16 MFMA: acc[0..3][nb..nb+3] += U (o-frags) x X (px-frags)
#define CL(U0, U1, U2, U3, X0, X1, X2, X3, nb)                                      \
  acc[0][(nb)+0] = __builtin_amdgcn_mfma_f32_16x16x32_bf16(U0, X0, acc[0][(nb)+0], 0, 0, 0); \
  acc[0][(nb)+1] = __builtin_amdgcn_mfma_f32_16x16x32_bf16(U0, X1, acc[0][(nb)+1], 0, 0, 0); \
  acc[0][(nb)+2] = __builtin_amdgcn_mfma_f32_16x16x32_bf16(U0, X2, acc[0][(nb)+2], 0, 0, 0); \
  acc[0][(nb)+3] = __builtin_amdgcn_mfma_f32_16x16x32_bf16(U0, X3, acc[0][(nb)+3], 0, 0, 0); \
  acc[1][(nb)+0] = __builtin_amdgcn_mfma_f32_16x16x32_bf16(U1, X0, acc[1][(nb)+0], 0, 0, 0); \
  acc[1][(nb)+1] = __builtin_amdgcn_mfma_f32_16x16x32_bf16(U1, X1, acc[1][(nb)+1], 0, 0, 0); \
  acc[1][(nb)+2] = __builtin_amdgcn_mfma_f32_16x16x32_bf16(U1, X2, acc[1][(nb)+2], 0, 0, 0); \
  acc[1][(nb)+3] = __builtin_amdgcn_mfma_f32_16x16x32_bf16(U1, X3, acc[1][(nb)+3], 0, 0, 0); \
  acc[2][(nb)+0] = __builtin_amdgcn_mfma_f32_16x16x32_bf16(U2, X0, acc[2][(nb)+0], 0, 0, 0); \
  acc[2][(nb)+1] = __builtin_amdgcn_mfma_f32_16x16x32_bf16(U2, X1, acc[2][(nb)+1], 0, 0, 0); \
  acc[2][(nb)+2] = __builtin_amdgcn_mfma_f32_16x16x32_bf16(U2, X2, acc[2][(nb)+2], 0, 0, 0); \
  acc[2][(nb)+3] = __builtin_amdgcn_mfma_f32_16x16x32_bf16(U2, X3, acc[2][(nb)+3], 0, 0, 0); \
  acc[3][(nb)+0] = __builtin_amdgcn_mfma_f32_16x16x32_bf16(U3, X0, acc[3][(nb)+0], 0, 0, 0); \
  acc[3][(nb)+1] = __builtin_amdgcn_mfma_f32_16x16x32_bf16(U3, X1, acc[3][(nb)+1], 0, 0, 0); \
  acc[3][(nb)+2] = __builtin_amdgcn_mfma_f32_16x16x32_bf16(U3, X2, acc[3][(nb)+2], 0, 0, 0); \
  acc[3][(nb)+3] = __builtin_amdgcn_mfma_f32_16x16x32_bf16(U3, X3, acc[3][(nb)+3], 0, 0, 0);

#define SB __builtin_amdgcn_sched_barrier(0);
#define P1 __builtin_amdgcn_s_setprio(1);
#define P0 __builtin_amdgcn_s_setprio(0);

// 9 taps, kw-major (consumed W t-order: 0,3,6,1,4,7,2,5,8). Register packs
// written out explicitly (a macro pack counts as ONE argument -- R12 bug).
#define NINE_TAPS(A0, A1, A2, A3, B0, B1, B2, B3, XB_)                        \
  /* kw0,kh0: use A(Wt0); load B=Wt3 */                                       \
  WLOAD(B0, B1, B2, B3, 196608)                                               \
  XLOAD(xa0, xa1, xa2, xa3, XB_, xpo[0])                                      \
  XLOAD(xb0, xb1, xb2, xb3, XB_, xpo[0] + 4224)                               \
  SB P1 CL(A0, A1, A2, A3, xa0, xa1, xa2, xa3, 0)                             \
        CL(A0, A1, A2, A3, xb0, xb1, xb2, xb3, 4) P0                          \
  /* kw0,kh1: use B(Wt3); load A=Wt6; reuse xb(row1); fresh xa=row2 */        \
  WLOAD(A0, A1, A2, A3, -327680)                                              \
  XLOAD(xa0, xa1, xa2, xa3, XB_, xpo[0] + 8448)                               \
  SB P1 CL(B0, B1, B2, B3, xb0, xb1, xb2, xb3, 0)                             \
        CL(B0, B1, B2, B3, xa0, xa1, xa2, xa3, 4) P0                          \
  /* kw0,kh2: use A(Wt6); load B=Wt1; reuse xa(row2); fresh xb=row3 */        \
  WLOAD(B0, B1, B2, B3, 196608)                                               \
  XLOAD(xb0, xb1, xb2, xb3, XB_, xpo[0] + 12672)                              \
  SB P1 CL(A0, A1, A2, A3, xa0, xa1, xa2, xa3, 0)                             \
        CL(A0, A1, A2, A3, xb0, xb1, xb2, xb3, 4) P0                          \
  /* kw1,kh0: use B(Wt1); load A=Wt4 */                                       \
  WLOAD(A0, A1, A2, A3, 196608)                                               \
  XLOAD(xa0, xa1, xa2, xa3, XB_, xpo[1])                                      \
  XLOAD(xb0, xb1, xb2, xb3, XB_, xpo[1] + 4224)                               \
  SB P1 CL(B0, B1, B2, B3, xa0, xa1, xa2, xa3, 0)                             \
        CL(B0, B1, B2, B3, xb0, xb1, xb2, xb3, 4) P0                          \
  /* kw1,kh1: use A(Wt4); load B=Wt7; reuse xb; fresh xa */                   \
  WLOAD(B0, B1, B2, B3, -327680)                                              \
  XLOAD(xa0, xa1, xa2, xa3, XB_, xpo[1] + 8448)                               \
  SB P1 CL(A0, A1, A2, A3, xb0, xb1, xb2, xb3, 0)                             \
        CL(A0, A1, A2, A3, xa0, xa1, xa2, xa3, 4) P0                          \
  /* kw1,kh2: use B(Wt7); load A=Wt2; reuse xa; fresh xb */                   \
  WLOAD(A0, A1, A2, A3, 196608)                                               \
  XLOAD(xb0, xb1, xb2, xb3, XB_, xpo[1] + 12672)                              \
  SB P1 CL(B0, B1, B2, B3, xa0, xa1, xa2, xa3, 0)                             \
        CL(B0, B1, B2, B3, xb0, xb1, xb2, xb3, 4) P0                          \
  /* kw2,kh0: use A(Wt2); load B=Wt5 */                                       \
  WLOAD(B0, B1, B2, B3, 196608)                                               \
  XLOAD(xa0, xa1, xa2, xa3, XB_, xpo[2])                                      \
  XLOAD(xb0, xb1, xb2, xb3, XB_, xpo[2] + 4224)                               \
  SB P1 CL(A0, A1, A2, A3, xa0, xa1, xa2, xa3, 0)                             \
        CL(A0, A1, A2, A3, xb0, xb1, xb2, xb3, 4) P0                          \
  /* kw2,kh1: use B(Wt5); load A=Wt8; reuse xb; fresh xa */                   \
  WLOAD(A0, A1, A2, A3, -516096)                                              \
  XLOAD(xa0, xa1, xa2, xa3, XB_, xpo[2] + 8448)                               \
  SB P1 CL(B0, B1, B2, B3, xb0, xb1, xb2, xb3, 0)                             \
        CL(B0, B1, B2, B3, xa0, xa1, xa2, xa3, 4) P0                          \
  /* kw2,kh2: use A(Wt8); load B=Wt0(next chunk); reuse xa; fresh xb */       \
  WLOAD(B0, B1, B2, B3, 196608)                                               \
  XLOAD(xb0, xb1, xb2, xb3, XB_, xpo[2] + 12672)                              \
  SB P1 CL(A0, A1, A2, A3, xa0, xa1, xa2, xa3, 0)                             \
        CL(A0, A1, A2, A3, xb0, xb1, xb2, xb3, 4) P0

#define CHUNK_BARRIER                                  \
  asm volatile("s_waitcnt vmcnt(4)" ::: "memory");     \
  __builtin_amdgcn_s_barrier();

  stage(0);
  // prologue: W(t0,cb0) -> A; wptr -> (t3,cb0) [kw-major consumed order]
  wa0 = *(const bf16x8*)(wptr);
  wa1 = *(const bf16x8*)(wptr + 512);
  wa2 = *(const bf16x8*)(wptr + 1024);
  wa3 = *(const bf16x8*)(wptr + 1536);
  wptr += 196608;
  __syncthreads();  // full drain once: X(0) + A ready

  const char* xbE = (const char*)&xlds[0][0];
  const char* xbO = (const char*)&xlds[1][0];

  for (int cc = 0; cc < 4; ++cc) {
    // even chunk cb = 2cc (buf 0, starts with set A)
    {
      const int cb = 2 * cc;
      if (cb < 7) stage(1);
      NINE_TAPS(wa0, wa1, wa2, wa3, wb0, wb1, wb2, wb3, xbE)
      CHUNK_BARRIER
    }
    // odd chunk cb = 2cc+1 (buf 1, starts with set B)
    {
      const int cb = 2 * cc + 1;
      if (cb < 7) stage(0);
      NINE_TAPS(wb0, wb1, wb2, wb3, wa0, wa1, wa2, wa3, xbO)
      CHUNK_BARRIER
    }
  }

  // Epilogue: wave writes 64 O x 2 rows x 64 cols.
#pragma unroll
  for (int mf = 0; mf < 4; ++mf) {
#pragma unroll
    for (int nf = 0; nf < 8; ++nf) {
      f32x4 v = acc[mf][nf];
      const int h    = h0 + rp * 2 + (nf >> 2);
      const int wcol = (nf & 3) * 16 + lm;
#pragma unroll
      for (int i = 0; i < 4; ++i) {
        const int o = ob + wm + mf * 16 + lq * 4 + i;
        y[(((size_t)b * NO + o) * NH + h) * NW + wcol] = v[i];
      }
    }
  }
#undef WLOAD
#undef XLOAD
#undef CL
#undef SB
#undef P1
#undef P0
#undef NINE_TAPS
#undef CHUNK_BARRIER
}

// =====================================================================
// FALLBACK PATH (proven R1 kernels) — used if ws_size is too small
// =====================================================================

__global__ __launch_bounds__(256) void pool_k(const float* __restrict__ x,
                                              float* __restrict__ pooled) {
  const int bc  = blockIdx.x;
  const int tid = threadIdx.x;
  const float4* base = (const float4*)(x + (size_t)bc * (NH * NW));
  float s = 0.f;
#pragma unroll
  for (int i = 0; i < 4; ++i) {
    float4 v = base[tid + 256 * i];
    s += v.x + v.y + v.z + v.w;
  }
#pragma unroll
  for (int off = 32; off > 0; off >>= 1) s += __shfl_down(s, off, 64);
  __shared__ float ws[4];
  if ((tid & 63) == 0) ws[tid >> 6] = s;
  __syncthreads();
  if (tid == 0) pooled[bc] = (ws[0] + ws[1] + ws[2] + ws[3]) * (1.f / (NH * NW));
}

__global__ __launch_bounds__(64) void router_k(const float* __restrict__ pooled,
                                               const float* __restrict__ rw,
                                               const float* __restrict__ rb,
                                               float* __restrict__ attn) {
  const int b = blockIdx.x, t = threadIdx.x;
  float p0 = 0.f, p1 = 0.f, p2 = 0.f, p3 = 0.f;
  for (int c = t; c < NC; c += 64) {
    float pv = pooled[b * NC + c];
    p0 += pv * rw[0 * NC + c];
    p1 += pv * rw[1 * NC + c];
    p2 += pv * rw[2 * NC + c];
    p3 += pv * rw[3 * NC + c];
  }
#pragma unroll
  for (int off = 32; off > 0; off >>= 1) {
    p0 += __shfl_down(p0, off, 64);
    p1 += __shfl_down(p1, off, 64);
    p2 += __shfl_down(p2, off, 64);
    p3 += __shfl_down(p3, off, 64);
  }
  if (t == 0) {
    float l0 = p0 + rb[0], l1 = p1 + rb[1], l2 = p2 + rb[2], l3 = p3 + rb[3];
    float m  = fmaxf(fmaxf(l0, l1), fmaxf(l2, l3));
    float e0 = expf(l0 - m), e1 = expf(l1 - m), e2 = expf(l2 - m), e3 = expf(l3 - m);
    float inv = 1.f / (e0 + e1 + e2 + e3);
    attn[b * 4 + 0] = e0 * inv;
    attn[b * 4 + 1] = e1 * inv;
    attn[b * 4 + 2] = e2 * inv;
    attn[b * 4 + 3] = e3 * inv;
  }
}

__global__ __launch_bounds__(256) void conv_k(const float* __restrict__ x,
                                              const unsigned short* __restrict__ wmix,
                                              float* __restrict__ y) {
  const int ptile = blockIdx.x;
  const int ob    = blockIdx.y * 128;
  const int b     = blockIdx.z;
  const int tid   = threadIdx.x;
  const int lane  = tid & 63;
  const int wid   = tid >> 6;
  const int wm    = (wid >> 1) * 64;
  const int wrow  = wid & 1;
  const int h0    = ptile * 2;
  const int lm = lane & 15;
  const int lq = lane >> 4;
  const int g8 = lq * 8;

  __shared__ unsigned short xlds[4 * 66 * 32];
  __shared__ unsigned short wlds[2][128 * 32];

  f32x4 acc[4][4];
#pragma unroll
  for (int i = 0; i < 4; ++i)
#pragma unroll
    for (int j = 0; j < 4; ++j) acc[i][j] = {0.f, 0.f, 0.f, 0.f};

  const int sr  = tid >> 6;
  const int scp = tid & 15;
  const int scg = (tid >> 4) & 3;
  const int gh  = h0 - 1 + sr;
  const bool hok = (gh >= 0) && (gh < NH);

  for (int cb = 0; cb < 8; ++cb) {
    {
      const float* xr0 =
          x + (((size_t)(b * NC + cb * 32 + 2 * scp) * NH + (hok ? gh : 0)) * NW);
      const float* xr1 = xr0 + (size_t)NH * NW;
      for (int k = 0; k < 17; ++k) {
        int col = scg + 4 * k;
        if (col < 66) {
          int w   = col - 1;
          bool ok = hok && (w >= 0) && (w < NW);
          float f0 = ok ? xr0[w] : 0.f;
          float f1 = ok ? xr1[w] : 0.f;
          uint32_t pk = (uint32_t)f2bf(f0) | ((uint32_t)f2bf(f1) << 16);
          *(uint32_t*)&xlds[(sr * 66 + col) * 32 + 2 * scp] = pk;
        }
      }
    }
    const size_t wchunk = (size_t)(b * 9) * 65536 + (size_t)cb * 8192 + (size_t)ob * 32;
    auto stageW = [&](int t, int buf) {
      const unsigned short* src = wmix + wchunk + (size_t)t * 65536 + tid * 8;
      char* dst = (char*)&wlds[buf][0] + (tid >> 6) * 1024;
      __builtin_amdgcn_global_load_lds((const __attribute__((address_space(1))) void*)src,
                                       (__attribute__((address_space(3))) void*)dst,
                                       16, 0, 0);
      __builtin_amdgcn_global_load_lds(
          (const __attribute__((address_space(1))) void*)(src + 2048),
          (__attribute__((address_space(3))) void*)(dst + 4096), 16, 0, 0);
    };
    stageW(0, 0);
    __syncthreads();

#pragma unroll
    for (int t = 0; t < 9; ++t) {
      if (t < 8) stageW(t + 1, (t + 1) & 1);
      const int kh = t / 3, kw = t % 3;
      const unsigned short* wb = &wlds[t & 1][0];
      bf16x8 af[4], bfr[4];
#pragma unroll
      for (int mf = 0; mf < 4; ++mf)
        af[mf] = *(const bf16x8*)&wb[(wm + mf * 16 + lm) * 32 + g8];
#pragma unroll
      for (int nf = 0; nf < 4; ++nf)
        bfr[nf] = *(const bf16x8*)&xlds[((wrow + kh) * 66 + (nf * 16 + lm + kw)) * 32 + g8];
#pragma unroll
      for (int mf = 0; mf < 4; ++mf)
#pragma unroll
        for (int nf = 0; nf < 4; ++nf)
          acc[mf][nf] =
              __builtin_amdgcn_mfma_f32_16x16x32_bf16(af[mf], bfr[nf], acc[mf][nf], 0, 0, 0);
      __syncthreads();
    }
  }

  const int h = h0 + wrow;
#pragma unroll
  for (int mf = 0; mf < 4; ++mf) {
#pragma unroll
    for (int nf = 0; nf < 4; ++nf) {
      f32x4 v = acc[mf][nf];
      int wcol = nf * 16 + lm;
#pragma unroll
      for (int i = 0; i < 4; ++i) {
        int o = ob + wm + mf * 16 + lq * 4 + i;
        y[(((size_t)b * NO + o) * NH + h) * NW + wcol] = v[i];
      }
    }
  }
}

// =====================================================================

extern "C" void kernel_launch(void* const* d_in, const int* in_sizes, int n_in,
                              void* d_out, int out_size, void* d_ws, size_t ws_size,
                              hipStream_t stream) {
  const float* x  = (const float*)d_in[0];   // [32,256,64,64]
  const float* rw = (const float*)d_in[1];   // [4,256,1,1]
  const float* rb = (const float*)d_in[2];   // [4]
  const float* ew = (const float*)d_in[3];   // [4,256,256,3,3]
  float* yout = (float*)d_out;               // [32,256,64,64] fp32

  float* pooled = (float*)d_ws;
  float* attn   = (float*)((char*)d_ws + 32768);
  unsigned short* wmix = (unsigned short*)((char*)d_ws + 65536);
  const size_t OFF_ROWSUM = 65536 + 37748736;
  const size_t OFF_XT     = OFF_ROWSUM + 2097152;
  // zpage MUST be at xT + 64MB (conv_k8 addresses it as xT + 33554432 elems)
  const size_t OFF_ZERO   = OFF_XT + 67108864;
  const size_t NEED       = OFF_ZERO + 4096;

  if (ws_size >= NEED) {
    float* rowsum = (float*)((char*)d_ws + OFF_ROWSUM);
    unsigned short* xT = (unsigned short*)((char*)d_ws + OFF_XT);
    uint32_t* zpage = (uint32_t*)((char*)d_ws + OFF_ZERO);
    xt_k<<<2048, 256, 0, stream>>>(x, xT, rowsum);
    router2_k<<<32, 256, 0, stream>>>(rowsum, rw, rb, attn, zpage);
    wmix_k2<<<2304, 256, 0, stream>>>(ew, attn, wmix);
    conv_k8<<<1024, 256, 0, stream>>>(xT, wmix, yout);
  } else {
    pool_k<<<NB * NC, 256, 0, stream>>>(x, pooled);
    router_k<<<NB, 64, 0, stream>>>(pooled, rw, rb, attn);
    wmix_k2<<<2304, 256, 0, stream>>>(ew, attn, wmix);
    conv_k<<<dim3(32, 2, 32), 256, 0, stream>>>(x, wmix, yout);
  }
}

// Round 14
// 186.538 us; speedup vs baseline: 1.1298x; 1.1298x over previous
//
#include <hip/hip_runtime.h>
#include <hip/hip_bf16.h>
#include <stdint.h>

// Problem constants (B,C,H,W = 32,256,64,64; E=4, O=256, K=3)
#define NB 32
#define NC 256
#define NH 64
#define NW 64
#define NE 4
#define NO 256

typedef __bf16 bf16x8 __attribute__((ext_vector_type(8)));
typedef float  f32x4  __attribute__((ext_vector_type(4)));

__device__ __forceinline__ unsigned short f2bf(float f) {
  union { float f; uint32_t u; } v; v.f = f;
  uint32_t u = v.u;
  uint32_t r = (u + 0x7FFFu + ((u >> 16) & 1u)) >> 16;  // RNE
  return (unsigned short)r;
}

// =====================================================================
// NEW PATH
// =====================================================================

// ---- Kernel A: transpose x (NCHW fp32) -> xT (NHWC bf16) + per-(b,h) rowsums
__global__ __launch_bounds__(256) void xt_k(const float* __restrict__ x,
                                            unsigned short* __restrict__ xT,
                                            float* __restrict__ rowsum) {
  const int bh = blockIdx.x;            // b*64 + h
  const int tid = threadIdx.x;
  const int ci = tid >> 4;              // 0..15 channel-in-pass
  const int wq = (tid & 15) * 4;        // w quad
  __shared__ unsigned short t_lds[256 * 66];

#pragma unroll 4
  for (int p = 0; p < 16; ++p) {
    const int c = p * 16 + ci;
    const float4 v = *(const float4*)&x[(((size_t)(blockIdx.x >> 6) * 256 + c) * 64 +
                                         (bh & 63)) * 64 + wq];
    uint32_t p0 = (uint32_t)f2bf(v.x) | ((uint32_t)f2bf(v.y) << 16);
    uint32_t p1 = (uint32_t)f2bf(v.z) | ((uint32_t)f2bf(v.w) << 16);
    *(uint32_t*)&t_lds[c * 66 + wq]     = p0;
    *(uint32_t*)&t_lds[c * 66 + wq + 2] = p1;
    float s = (v.x + v.y) + (v.z + v.w);
    s += __shfl_down(s, 8, 16);
    s += __shfl_down(s, 4, 16);
    s += __shfl_down(s, 2, 16);
    s += __shfl_down(s, 1, 16);
    if ((tid & 15) == 0) rowsum[((size_t)bh << 8) + c] = s;
  }
  __syncthreads();
#pragma unroll
  for (int i = 0; i < 8; ++i) {
    const int m  = tid + (i << 8);
    const int w  = m >> 5;
    const int cg = m & 31;
    uint32_t q0 = (uint32_t)t_lds[(cg * 8 + 0) * 66 + w] |
                  ((uint32_t)t_lds[(cg * 8 + 1) * 66 + w] << 16);
    uint32_t q1 = (uint32_t)t_lds[(cg * 8 + 2) * 66 + w] |
                  ((uint32_t)t_lds[(cg * 8 + 3) * 66 + w] << 16);
    uint32_t q2 = (uint32_t)t_lds[(cg * 8 + 4) * 66 + w] |
                  ((uint32_t)t_lds[(cg * 8 + 5) * 66 + w] << 16);
    uint32_t q3 = (uint32_t)t_lds[(cg * 8 + 6) * 66 + w] |
                  ((uint32_t)t_lds[(cg * 8 + 7) * 66 + w] << 16);
    uint4 q = {q0, q1, q2, q3};
    *(uint4*)&xT[(((size_t)bh << 6) + w) * 256 + cg * 8] = q;
  }
}

// ---- Kernel B: reduce rowsums -> pooled -> logits -> softmax -> attn; zero zpage
__global__ __launch_bounds__(256) void router2_k(const float* __restrict__ rowsum,
                                                 const float* __restrict__ rw,
                                                 const float* __restrict__ rb,
                                                 float* __restrict__ attn,
                                                 uint32_t* __restrict__ zpage) {
  const int b = blockIdx.x, tid = threadIdx.x;
  if (b == 0) { uint4 z = {0, 0, 0, 0}; ((uint4*)zpage)[tid] = z; }
  float s = 0.f;
#pragma unroll 8
  for (int h = 0; h < 64; ++h) s += rowsum[((size_t)(b * 64 + h) << 8) + tid];
  __shared__ float pl[256];
  __shared__ float lg[4];
  pl[tid] = s * (1.f / 4096.f);
  __syncthreads();
  const int e = tid >> 6, ln = tid & 63;
  float d = pl[ln]       * rw[e * 256 + ln] +
            pl[ln + 64]  * rw[e * 256 + ln + 64] +
            pl[ln + 128] * rw[e * 256 + ln + 128] +
            pl[ln + 192] * rw[e * 256 + ln + 192];
#pragma unroll
  for (int off = 32; off > 0; off >>= 1) d += __shfl_down(d, off, 64);
  if (ln == 0) lg[e] = d + rb[e];
  __syncthreads();
  if (tid == 0) {
    float l0 = lg[0], l1 = lg[1], l2 = lg[2], l3 = lg[3];
    float m  = fmaxf(fmaxf(l0, l1), fmaxf(l2, l3));
    float e0 = expf(l0 - m), e1 = expf(l1 - m), e2 = expf(l2 - m), e3 = expf(l3 - m);
    float inv = 1.f / (e0 + e1 + e2 + e3);
    attn[b * 4 + 0] = e0 * inv;
    attn[b * 4 + 1] = e1 * inv;
    attn[b * 4 + 2] = e2 * inv;
    attn[b * 4 + 3] = e3 * inv;
  }
}

// ---- Kernel C: mixed weights; each thread owns one (t,cb,o,c32), loops over b
__global__ __launch_bounds__(256) void wmix_k2(const float* __restrict__ ew,
                                               const float* __restrict__ attn,
                                               unsigned short* __restrict__ wmix) {
  __shared__ float at[128];
  if (threadIdx.x < 128) at[threadIdx.x] = attn[threadIdx.x];
  __syncthreads();
  const int i   = blockIdx.x * 256 + threadIdx.x;   // 0..589823
  const int c32 = i & 31;
  const int o   = (i >> 5) & 255;
  const int cb  = (i >> 13) & 7;
  const int t   = i >> 16;                          // 0..8
  const int c   = cb * 32 + c32;
  const size_t estride = (size_t)NO * NC * 9;       // 589824
  const size_t wi = ((size_t)o * NC + c) * 9 + t;
  const float e0 = ew[wi], e1 = ew[wi + estride], e2 = ew[wi + 2 * estride],
              e3 = ew[wi + 3 * estride];
  const size_t outbase = ((size_t)t * 8 + cb) * 8192 + o * 32 + c32;
#pragma unroll 4
  for (int b = 0; b < 32; ++b) {
    float s = at[b * 4] * e0 + at[b * 4 + 1] * e1 + at[b * 4 + 2] * e2 +
              at[b * 4 + 3] * e3;
    wmix[outbase + (size_t)b * 589824] = f2bf(s);
  }
}

// ---- Kernel D (R14 = R11 anchor): 128 O x 256 px block, 4 waves, wave tile
// 64 O x 128 px; each tap = two 16-MFMA half-taps sharing ONE 4-register X
// set. W A/B rotation, soff-stepped DMA staging, vmcnt(4)+s_barrier/chunk.
// Best measured: conv 138.4 us, MfmaUtil 48%, no spill. (R12/R13's kw-major
// reorder spilled: at acc=128 + 2 waves/SIMD every extra live VGPR spills.)
__global__ __launch_bounds__(256, 2) void conv_k7(
    const unsigned short* __restrict__ xT, const unsigned short* __restrict__ wmix,
    float* __restrict__ y) {
  const int bid   = blockIdx.x;        // 1024 blocks
  const int r     = bid >> 3;          // 0..127
  const int ptile = r & 15;            // 16 tiles of 4 rows
  const int ob    = ((r >> 4) & 1) * 128;
  const int b     = (bid & 7) + ((r >> 5) << 3);
  const int tid   = threadIdx.x;
  const int lane  = tid & 63;
  const int wid   = tid >> 6;          // 0..3
  const int wm    = (wid >> 1) * 64;   // O half
  const int rp    = wid & 1;           // row-pair within 4-row tile
  const int h0    = ptile * 4;
  const int lm    = lane & 15;
  const int lq    = lane >> 4;

  // 6 halo rows x 66 cols x 32 ch bf16 = 25344 B; padded to 25600 B
  __shared__ unsigned short xlds[2][12800];

  // Persistent staging offsets (elements, relative to xT). Zero-page lanes
  // point at xT + 64MB (zpage) and step +32/chunk (drift <=448B, zeroed).
  uint32_t soff[7];
#pragma unroll
  for (int i = 0; i < 7; ++i) {
    const int chunk = wid + 4 * i;
    const int d   = chunk * 64 + lane;
    const int row = d / 264;
    const int rem = d - row * 264;
    const int col = rem >> 2;
    const int s   = rem & 3;
    const int g   = s ^ ((col >> 1) & 3);
    const int gh  = h0 - 1 + row;
    const int w   = col - 1;
    const bool ok = (d < 1584) && (gh >= 0) && (gh < NH) && (w >= 0) && (w < NW);
    soff[i] = ok ? (uint32_t)(((b * 64 + gh) * 64 + w) << 8) + g * 8
                 : 33554432u + lane * 8;   // -> zpage
  }

  auto stage = [&](int buf) {
#pragma unroll
    for (int i = 0; i < 7; ++i) {
      const int chunk = wid + 4 * i;
      if (chunk < 25) {   // wave-uniform
        const unsigned short* src = xT + soff[i];
        char* dst = (char*)&xlds[buf][0] + chunk * 1024;
        __builtin_amdgcn_global_load_lds(
            (const __attribute__((address_space(1))) void*)src,
            (__attribute__((address_space(3))) void*)dst, 16, 0, 0);
      }
      soff[i] += 32;   // next c-chunk (64B)
    }
  };

  // Swizzled byte offset per kw (col-group j -> +1024B imm; kh -> +4224B imm).
  uint32_t xpo[3];
#pragma unroll
  for (int kw = 0; kw < 3; ++kw) {
    const int col = lm + kw;
    xpo[kw] = (uint32_t)(rp * 8448) +
              (((uint32_t)col << 6) | ((uint32_t)(lq ^ ((col >> 1) & 3)) << 4));
  }

  f32x4 acc[4][8];
#pragma unroll
  for (int i = 0; i < 4; ++i)
#pragma unroll
    for (int j = 0; j < 8; ++j) acc[i][j] = {0.f, 0.f, 0.f, 0.f};

  // Loop-carried W pointer; set (t,cb) base = (t*8+cb)*8192 elements.
  const unsigned short* wptr =
      wmix + (size_t)b * 589824 + (ob + wm + lm) * 32 + lq * 8;

  bf16x8 wa0, wa1, wa2, wa3, wb0, wb1, wb2, wb3;
  bf16x8 x0, x1, x2, x3;

// Half-tap: 4 X ds_reads (one input row) + 16 MFMA into acc[.][base..base+3]
#define HALF(U0, U1, U2, U3, XB, xoffB, nbase)                                      \
  {                                                                                 \
    x0 = *(const bf16x8*)((XB) + (xoffB));                                          \
    x1 = *(const bf16x8*)((XB) + (xoffB) + 1024);                                   \
    x2 = *(const bf16x8*)((XB) + (xoffB) + 2048);                                   \
    x3 = *(const bf16x8*)((XB) + (xoffB) + 3072);                                   \
    __builtin_amdgcn_sched_barrier(0);                                              \
    __builtin_amdgcn_s_setprio(1);                                                  \
    acc[0][(nbase)+0] = __builtin_amdgcn_mfma_f32_16x16x32_bf16(U0, x0, acc[0][(nbase)+0], 0, 0, 0); \
    acc[0][(nbase)+1] = __builtin_amdgcn_mfma_f32_16x16x32_bf16(U0, x1, acc[0][(nbase)+1], 0, 0, 0); \
    acc[0][(nbase)+2] = __builtin_amdgcn_mfma_f32_16x16x32_bf16(U0, x2, acc[0][(nbase)+2], 0, 0, 0); \
    acc[0][(nbase)+3] = __builtin_amdgcn_mfma_f32_16x16x32_bf16(U0, x3, acc[0][(nbase)+3], 0, 0, 0); \
    acc[1][(nbase)+0] = __builtin_amdgcn_mfma_f32_16x16x32_bf16(U1, x0, acc[1][(nbase)+0], 0, 0, 0); \
    acc[1][(nbase)+1] = __builtin_amdgcn_mfma_f32_16x16x32_bf16(U1, x1, acc[1][(nbase)+1], 0, 0, 0); \
    acc[1][(nbase)+2] = __builtin_amdgcn_mfma_f32_16x16x32_bf16(U1, x2, acc[1][(nbase)+2], 0, 0, 0); \
    acc[1][(nbase)+3] = __builtin_amdgcn_mfma_f32_16x16x32_bf16(U1, x3, acc[1][(nbase)+3], 0, 0, 0); \
    acc[2][(nbase)+0] = __builtin_amdgcn_mfma_f32_16x16x32_bf16(U2, x0, acc[2][(nbase)+0], 0, 0, 0); \
    acc[2][(nbase)+1] = __builtin_amdgcn_mfma_f32_16x16x32_bf16(U2, x1, acc[2][(nbase)+1], 0, 0, 0); \
    acc[2][(nbase)+2] = __builtin_amdgcn_mfma_f32_16x16x32_bf16(U2, x2, acc[2][(nbase)+2], 0, 0, 0); \
    acc[2][(nbase)+3] = __builtin_amdgcn_mfma_f32_16x16x32_bf16(U2, x3, acc[2][(nbase)+3], 0, 0, 0); \
    acc[3][(nbase)+0] = __builtin_amdgcn_mfma_f32_16x16x32_bf16(U3, x0, acc[3][(nbase)+0], 0, 0, 0); \
    acc[3][(nbase)+1] = __builtin_amdgcn_mfma_f32_16x16x32_bf16(U3, x1, acc[3][(nbase)+1], 0, 0, 0); \
    acc[3][(nbase)+2] = __builtin_amdgcn_mfma_f32_16x16x32_bf16(U3, x2, acc[3][(nbase)+2], 0, 0, 0); \
    acc[3][(nbase)+3] = __builtin_amdgcn_mfma_f32_16x16x32_bf16(U3, x3, acc[3][(nbase)+3], 0, 0, 0); \
    __builtin_amdgcn_s_setprio(0);                                                  \
  }

#define TAPBODY(U0, U1, U2, U3, L0, L1, L2, L3, XB, khv, kwv, delta)                \
  {                                                                                 \
    L0 = *(const bf16x8*)(wptr);                                                    \
    L1 = *(const bf16x8*)(wptr + 512);                                              \
    L2 = *(const bf16x8*)(wptr + 1024);                                             \
    L3 = *(const bf16x8*)(wptr + 1536);                                             \
    wptr += (delta);                                                                \
    HALF(U0, U1, U2, U3, XB, xpo[(kwv)] + (khv) * 4224, 0)                          \
    HALF(U0, U1, U2, U3, XB, xpo[(kwv)] + ((khv) + 1) * 4224, 4)                    \
  }

#define NINE_TAPS(A0, A1, A2, A3, B0, B1, B2, B3, XB)                       \
  TAPBODY(A0, A1, A2, A3, B0, B1, B2, B3, XB, 0, 0, 65536)                  \
  TAPBODY(B0, B1, B2, B3, A0, A1, A2, A3, XB, 0, 1, 65536)                  \
  TAPBODY(A0, A1, A2, A3, B0, B1, B2, B3, XB, 0, 2, 65536)                  \
  TAPBODY(B0, B1, B2, B3, A0, A1, A2, A3, XB, 1, 0, 65536)                  \
  TAPBODY(A0, A1, A2, A3, B0, B1, B2, B3, XB, 1, 1, 65536)                  \
  TAPBODY(B0, B1, B2, B3, A0, A1, A2, A3, XB, 1, 2, 65536)                  \
  TAPBODY(A0, A1, A2, A3, B0, B1, B2, B3, XB, 2, 0, 65536)                  \
  TAPBODY(B0, B1, B2, B3, A0, A1, A2, A3, XB, 2, 1, -516096)                \
  TAPBODY(A0, A1, A2, A3, B0, B1, B2, B3, XB, 2, 2, 65536)

#define CHUNK_BARRIER                                  \
  asm volatile("s_waitcnt vmcnt(4)" ::: "memory");     \
  __builtin_amdgcn_s_barrier();

  stage(0);
  // prologue: W(t0,cb0) -> A; wptr -> (t1,cb0)
  wa0 = *(const bf16x8*)(wptr);
  wa1 = *(const bf16x8*)(wptr + 512);
  wa2 = *(const bf16x8*)(wptr + 1024);
  wa3 = *(const bf16x8*)(wptr + 1536);
  wptr += 65536;
  __syncthreads();  // full drain once: X(0) + A ready

  const char* xbE = (const char*)&xlds[0][0];
  const char* xbO = (const char*)&xlds[1][0];

  for (int cc = 0; cc < 4; ++cc) {
    // even chunk cb = 2cc (buf 0, starts with set A)
    {
      const int cb = 2 * cc;
      if (cb < 7) stage(1);
      NINE_TAPS(wa0, wa1, wa2, wa3, wb0, wb1, wb2, wb3, xbE)
      CHUNK_BARRIER
    }
    // odd chunk cb = 2cc+1 (buf 1, starts with set B)
    {
      const int cb = 2 * cc + 1;
      if (cb < 7) stage(0);
      NINE_TAPS(wb0, wb1, wb2, wb3, wa0, wa1, wa2, wa3, xbO)
      CHUNK_BARRIER
    }
  }

  // Epilogue: wave writes 64 O x 2 rows x 64 cols.
#pragma unroll
  for (int mf = 0; mf < 4; ++mf) {
#pragma unroll
    for (int nf = 0; nf < 8; ++nf) {
      f32x4 v = acc[mf][nf];
      const int h    = h0 + rp * 2 + (nf >> 2);
      const int wcol = (nf & 3) * 16 + lm;
#pragma unroll
      for (int i = 0; i < 4; ++i) {
        const int o = ob + wm + mf * 16 + lq * 4 + i;
        y[(((size_t)b * NO + o) * NH + h) * NW + wcol] = v[i];
      }
    }
  }
#undef HALF
#undef TAPBODY
#undef NINE_TAPS
#undef CHUNK_BARRIER
}

// =====================================================================
// FALLBACK PATH (proven R1 kernels) — used if ws_size is too small
// =====================================================================

__global__ __launch_bounds__(256) void pool_k(const float* __restrict__ x,
                                              float* __restrict__ pooled) {
  const int bc  = blockIdx.x;
  const int tid = threadIdx.x;
  const float4* base = (const float4*)(x + (size_t)bc * (NH * NW));
  float s = 0.f;
#pragma unroll
  for (int i = 0; i < 4; ++i) {
    float4 v = base[tid + 256 * i];
    s += v.x + v.y + v.z + v.w;
  }
#pragma unroll
  for (int off = 32; off > 0; off >>= 1) s += __shfl_down(s, off, 64);
  __shared__ float ws[4];
  if ((tid & 63) == 0) ws[tid >> 6] = s;
  __syncthreads();
  if (tid == 0) pooled[bc] = (ws[0] + ws[1] + ws[2] + ws[3]) * (1.f / (NH * NW));
}

__global__ __launch_bounds__(64) void router_k(const float* __restrict__ pooled,
                                               const float* __restrict__ rw,
                                               const float* __restrict__ rb,
                                               float* __restrict__ attn) {
  const int b = blockIdx.x, t = threadIdx.x;
  float p0 = 0.f, p1 = 0.f, p2 = 0.f, p3 = 0.f;
  for (int c = t; c < NC; c += 64) {
    float pv = pooled[b * NC + c];
    p0 += pv * rw[0 * NC + c];
    p1 += pv * rw[1 * NC + c];
    p2 += pv * rw[2 * NC + c];
    p3 += pv * rw[3 * NC + c];
  }
#pragma unroll
  for (int off = 32; off > 0; off >>= 1) {
    p0 += __shfl_down(p0, off, 64);
    p1 += __shfl_down(p1, off, 64);
    p2 += __shfl_down(p2, off, 64);
    p3 += __shfl_down(p3, off, 64);
  }
  if (t == 0) {
    float l0 = p0 + rb[0], l1 = p1 + rb[1], l2 = p2 + rb[2], l3 = p3 + rb[3];
    float m  = fmaxf(fmaxf(l0, l1), fmaxf(l2, l3));
    float e0 = expf(l0 - m), e1 = expf(l1 - m), e2 = expf(l2 - m), e3 = expf(l3 - m);
    float inv = 1.f / (e0 + e1 + e2 + e3);
    attn[b * 4 + 0] = e0 * inv;
    attn[b * 4 + 1] = e1 * inv;
    attn[b * 4 + 2] = e2 * inv;
    attn[b * 4 + 3] = e3 * inv;
  }
}

__global__ __launch_bounds__(256) void conv_k(const float* __restrict__ x,
                                              const unsigned short* __restrict__ wmix,
                                              float* __restrict__ y) {
  const int ptile = blockIdx.x;
  const int ob    = blockIdx.y * 128;
  const int b     = blockIdx.z;
  const int tid   = threadIdx.x;
  const int lane  = tid & 63;
  const int wid   = tid >> 6;
  const int wm    = (wid >> 1) * 64;
  const int wrow  = wid & 1;
  const int h0    = ptile * 2;
  const int lm = lane & 15;
  const int lq = lane >> 4;
  const int g8 = lq * 8;

  __shared__ unsigned short xlds[4 * 66 * 32];
  __shared__ unsigned short wlds[2][128 * 32];

  f32x4 acc[4][4];
#pragma unroll
  for (int i = 0; i < 4; ++i)
#pragma unroll
    for (int j = 0; j < 4; ++j) acc[i][j] = {0.f, 0.f, 0.f, 0.f};

  const int sr  = tid >> 6;
  const int scp = tid & 15;
  const int scg = (tid >> 4) & 3;
  const int gh  = h0 - 1 + sr;
  const bool hok = (gh >= 0) && (gh < NH);

  for (int cb = 0; cb < 8; ++cb) {
    {
      const float* xr0 =
          x + (((size_t)(b * NC + cb * 32 + 2 * scp) * NH + (hok ? gh : 0)) * NW);
      const float* xr1 = xr0 + (size_t)NH * NW;
      for (int k = 0; k < 17; ++k) {
        int col = scg + 4 * k;
        if (col < 66) {
          int w   = col - 1;
          bool ok = hok && (w >= 0) && (w < NW);
          float f0 = ok ? xr0[w] : 0.f;
          float f1 = ok ? xr1[w] : 0.f;
          uint32_t pk = (uint32_t)f2bf(f0) | ((uint32_t)f2bf(f1) << 16);
          *(uint32_t*)&xlds[(sr * 66 + col) * 32 + 2 * scp] = pk;
        }
      }
    }
    const size_t wchunk = (size_t)(b * 9) * 65536 + (size_t)cb * 8192 + (size_t)ob * 32;
    auto stageW = [&](int t, int buf) {
      const unsigned short* src = wmix + wchunk + (size_t)t * 65536 + tid * 8;
      char* dst = (char*)&wlds[buf][0] + (tid >> 6) * 1024;
      __builtin_amdgcn_global_load_lds((const __attribute__((address_space(1))) void*)src,
                                       (__attribute__((address_space(3))) void*)dst,
                                       16, 0, 0);
      __builtin_amdgcn_global_load_lds(
          (const __attribute__((address_space(1))) void*)(src + 2048),
          (__attribute__((address_space(3))) void*)(dst + 4096), 16, 0, 0);
    };
    stageW(0, 0);
    __syncthreads();

#pragma unroll
    for (int t = 0; t < 9; ++t) {
      if (t < 8) stageW(t + 1, (t + 1) & 1);
      const int kh = t / 3, kw = t % 3;
      const unsigned short* wb = &wlds[t & 1][0];
      bf16x8 af[4], bfr[4];
#pragma unroll
      for (int mf = 0; mf < 4; ++mf)
        af[mf] = *(const bf16x8*)&wb[(wm + mf * 16 + lm) * 32 + g8];
#pragma unroll
      for (int nf = 0; nf < 4; ++nf)
        bfr[nf] = *(const bf16x8*)&xlds[((wrow + kh) * 66 + (nf * 16 + lm + kw)) * 32 + g8];
#pragma unroll
      for (int mf = 0; mf < 4; ++mf)
#pragma unroll
        for (int nf = 0; nf < 4; ++nf)
          acc[mf][nf] =
              __builtin_amdgcn_mfma_f32_16x16x32_bf16(af[mf], bfr[nf], acc[mf][nf], 0, 0, 0);
      __syncthreads();
    }
  }

  const int h = h0 + wrow;
#pragma unroll
  for (int mf = 0; mf < 4; ++mf) {
#pragma unroll
    for (int nf = 0; nf < 4; ++nf) {
      f32x4 v = acc[mf][nf];
      int wcol = nf * 16 + lm;
#pragma unroll
      for (int i = 0; i < 4; ++i) {
        int o = ob + wm + mf * 16 + lq * 4 + i;
        y[(((size_t)b * NO + o) * NH + h) * NW + wcol] = v[i];
      }
    }
  }
}

// =====================================================================

extern "C" void kernel_launch(void* const* d_in, const int* in_sizes, int n_in,
                              void* d_out, int out_size, void* d_ws, size_t ws_size,
                              hipStream_t stream) {
  const float* x  = (const float*)d_in[0];   // [32,256,64,64]
  const float* rw = (const float*)d_in[1];   // [4,256,1,1]
  const float* rb = (const float*)d_in[2];   // [4]
  const float* ew = (const float*)d_in[3];   // [4,256,256,3,3]
  float* yout = (float*)d_out;               // [32,256,64,64] fp32

  float* pooled = (float*)d_ws;
  float* attn   = (float*)((char*)d_ws + 32768);
  unsigned short* wmix = (unsigned short*)((char*)d_ws + 65536);
  const size_t OFF_ROWSUM = 65536 + 37748736;
  const size_t OFF_XT     = OFF_ROWSUM + 2097152;
  // zpage MUST be at xT + 64MB (conv_k7 addresses it as xT + 33554432 elems)
  const size_t OFF_ZERO   = OFF_XT + 67108864;
  const size_t NEED       = OFF_ZERO + 4096;

  if (ws_size >= NEED) {
    float* rowsum = (float*)((char*)d_ws + OFF_ROWSUM);
    unsigned short* xT = (unsigned short*)((char*)d_ws + OFF_XT);
    uint32_t* zpage = (uint32_t*)((char*)d_ws + OFF_ZERO);
    xt_k<<<2048, 256, 0, stream>>>(x, xT, rowsum);
    router2_k<<<32, 256, 0, stream>>>(rowsum, rw, rb, attn, zpage);
    wmix_k2<<<2304, 256, 0, stream>>>(ew, attn, wmix);
    conv_k7<<<1024, 256, 0, stream>>>(xT, wmix, yout);
  } else {
    pool_k<<<NB * NC, 256, 0, stream>>>(x, pooled);
    router_k<<<NB, 64, 0, stream>>>(pooled, rw, rb, attn);
    wmix_k2<<<2304, 256, 0, stream>>>(ew, attn, wmix);
    conv_k<<<dim3(32, 2, 32), 256, 0, stream>>>(x, wmix, yout);
  }
}